// Round 1
// baseline (172.473 us; speedup 1.0000x reference)
//
#include <hip/hip_runtime.h>

#define FIELDS  100000
#define FACTORS 16
#define BATCH   1024
#define BT      8            // batch rows per block
#define NCHUNK  8            // field chunks (one per XCD via round-robin)
#define FPC     (FIELDS / NCHUNK)   // 12500 fields per chunk
#define BLOCK   256

// Each block: BT batch rows x one field chunk.
// Thread t: field = fbase + (t>>1), factor-half = (t&1)*8.
// Per field: read 32B of W (coalesced, whole wave reads contiguous 8KB),
// read 8 x0 masks (coalesced, 2-way duplicated), 8x9 FMAs.
__global__ __launch_bounds__(BLOCK) void fm_partial(
    const int* __restrict__ x0, const float* __restrict__ W,
    float* __restrict__ ws)
{
    const int t     = threadIdx.x;
    const int bid   = blockIdx.x;
    const int bg    = bid >> 3;              // 0..127
    const int chunk = bid & (NCHUNK - 1);    // 0..7  -> XCD-local W slice
    const int b0    = bg * BT;
    const int fbeg  = chunk * FPC;
    const int fend  = fbeg + FPC;
    const int pair  = t >> 1;                // 0..127 field offset per step
    const int half  = t & 1;                 // which 8 factors

    float acc[BT][8];
    float qac[BT];
#pragma unroll
    for (int r = 0; r < BT; ++r) {
        qac[r] = 0.f;
#pragma unroll
        for (int j = 0; j < 8; ++j) acc[r][j] = 0.f;
    }

    const int* xb = x0 + (size_t)b0 * FIELDS;

    for (int f = fbeg + pair; f < fend; f += (BLOCK / 2)) {
        const float* wp = W + (size_t)f * FACTORS + half * 8;
        const float4 wa = *reinterpret_cast<const float4*>(wp);
        const float4 wb = *reinterpret_cast<const float4*>(wp + 4);
        const float ssq = wa.x*wa.x + wa.y*wa.y + wa.z*wa.z + wa.w*wa.w
                        + wb.x*wb.x + wb.y*wb.y + wb.z*wb.z + wb.w*wb.w;
#pragma unroll
        for (int r = 0; r < BT; ++r) {
            const int   xv = xb[(size_t)r * FIELDS + f];
            const float m  = (xv > 0) ? 1.0f : 0.0f;
            qac[r]    = fmaf(m, ssq,  qac[r]);
            acc[r][0] = fmaf(m, wa.x, acc[r][0]);
            acc[r][1] = fmaf(m, wa.y, acc[r][1]);
            acc[r][2] = fmaf(m, wa.z, acc[r][2]);
            acc[r][3] = fmaf(m, wa.w, acc[r][3]);
            acc[r][4] = fmaf(m, wb.x, acc[r][4]);
            acc[r][5] = fmaf(m, wb.y, acc[r][5]);
            acc[r][6] = fmaf(m, wb.z, acc[r][6]);
            acc[r][7] = fmaf(m, wb.w, acc[r][7]);
        }
    }

    // ---- wave-level reduce ----
    // s: sum over same-parity lanes (same factor-half): xor masks 2..32
    // q: sum over all 64 lanes: xor masks 1..32
#pragma unroll
    for (int r = 0; r < BT; ++r) {
#pragma unroll
        for (int off = 2; off < 64; off <<= 1) {
#pragma unroll
            for (int j = 0; j < 8; ++j)
                acc[r][j] += __shfl_xor(acc[r][j], off);
        }
#pragma unroll
        for (int off = 1; off < 64; off <<= 1)
            qac[r] += __shfl_xor(qac[r], off);
    }

    // ---- cross-wave combine + atomic flush ----
    __shared__ float red[4][BT][17];
    const int wave = t >> 6;
    const int lane = t & 63;
    if (lane < 2) {
#pragma unroll
        for (int r = 0; r < BT; ++r) {
#pragma unroll
            for (int j = 0; j < 8; ++j)
                red[wave][r][lane * 8 + j] = acc[r][j];
            if (lane == 0) red[wave][r][16] = qac[r];
        }
    }
    __syncthreads();
    if (t < BT * 17) {
        const int r = t / 17;
        const int j = t % 17;
        const float v = red[0][r][j] + red[1][r][j] + red[2][r][j] + red[3][r][j];
        atomicAdd(&ws[(b0 + r) * 17 + j], v);
    }
}

__global__ __launch_bounds__(BLOCK) void fm_final(
    const float* __restrict__ ws, float* __restrict__ out)
{
    const int b = blockIdx.x * BLOCK + threadIdx.x;
    if (b < BATCH) {
        const float* p = ws + b * 17;
        float ss = 0.f;
#pragma unroll
        for (int k = 0; k < FACTORS; ++k) ss += p[k] * p[k];
        out[b] = 0.5f * (ss - p[16]);
    }
}

extern "C" void kernel_launch(void* const* d_in, const int* in_sizes, int n_in,
                              void* d_out, int out_size, void* d_ws, size_t ws_size,
                              hipStream_t stream)
{
    const int*   x0 = (const int*)d_in[0];
    const float* W  = (const float*)d_in[1];
    float* out = (float*)d_out;
    float* ws  = (float*)d_ws;

    // zero the 1024x17 partial-sum buffer (s[16] + q per batch row)
    hipMemsetAsync(ws, 0, BATCH * 17 * sizeof(float), stream);

    fm_partial<<<dim3((BATCH / BT) * NCHUNK), dim3(BLOCK), 0, stream>>>(x0, W, ws);
    fm_final<<<dim3((BATCH + BLOCK - 1) / BLOCK), dim3(BLOCK), 0, stream>>>(ws, out);
}